// Round 2
// baseline (1855.038 us; speedup 1.0000x reference)
//
#include <hip/hip_runtime.h>

#define HID 32
#define LEAKY 0.01f
#define SE3NORM 0.17677669529663687f   // 1/sqrt(32)

// ---------------- stage 2: agg1[dst] += pos[src][0:2] ----------------
__global__ void k_edge_agg1(const int* __restrict__ ei, const float* __restrict__ pos,
                            float* __restrict__ agg1, int E) {
    int e = blockIdx.x * blockDim.x + threadIdx.x;
    if (e >= E) return;
    int s = ei[e];
    int d = ei[E + e];
    atomicAdd(&agg1[d * 2 + 0], pos[s * 3 + 0]);
    atomicAdd(&agg1[d * 2 + 1], pos[s * 3 + 1]);
}

// ------- stage 3: h1se = leaky(agg1@Wl1 + bl1 + x@Wr1) @ Wse1 * SE3NORM -------
__global__ void k_node_h1(const float* __restrict__ agg1, const float* __restrict__ pos,
                          const float* __restrict__ Wl1, const float* __restrict__ bl1,
                          const float* __restrict__ Wr1, const float* __restrict__ Wse1,
                          float* __restrict__ h1out, int N) {
    __shared__ float sWl1[2 * HID], sWr1[2 * HID], sbl1[HID], sWse1[HID * HID];
    for (int i = threadIdx.x; i < 2 * HID; i += blockDim.x) { sWl1[i] = Wl1[i]; sWr1[i] = Wr1[i]; }
    for (int i = threadIdx.x; i < HID; i += blockDim.x) sbl1[i] = bl1[i];
    for (int i = threadIdx.x; i < HID * HID; i += blockDim.x) sWse1[i] = Wse1[i];
    __syncthreads();
    int i = blockIdx.x * blockDim.x + threadIdx.x;
    if (i >= N) return;
    float a0 = agg1[2 * i], a1 = agg1[2 * i + 1];
    float x0 = pos[3 * i], x1 = pos[3 * i + 1];
    float h[HID];
#pragma unroll
    for (int j = 0; j < HID; j++) {
        float v = a0 * sWl1[j] + a1 * sWl1[HID + j] + sbl1[j] + x0 * sWr1[j] + x1 * sWr1[HID + j];
        h[j] = v > 0.f ? v : LEAKY * v;
    }
#pragma unroll
    for (int j = 0; j < HID; j++) {
        float acc = 0.f;
#pragma unroll
        for (int k = 0; k < HID; k++) acc += h[k] * sWse1[k * HID + j];
        h1out[(size_t)i * HID + j] = acc * SE3NORM;
    }
}

// ---------------- stage 4: agg2[dst] += h1se[src]  (8 threads/edge, float4) ----------------
__global__ void k_edge_agg2(const int* __restrict__ ei, const float* __restrict__ h1,
                            float* __restrict__ agg2, int E) {
    int gid = blockIdx.x * blockDim.x + threadIdx.x;
    int e = gid >> 3;
    int t = gid & 7;
    if (e >= E) return;
    int s = ei[e];
    int d = ei[E + e];
    const float4 v = *reinterpret_cast<const float4*>(&h1[(size_t)s * HID + t * 4]);
    float* base = &agg2[(size_t)d * HID + t * 4];
    atomicAdd(base + 0, v.x);
    atomicAdd(base + 1, v.y);
    atomicAdd(base + 2, v.z);
    atomicAdd(base + 3, v.w);
}

// ---------------- stage 5: second conv + skip + MLP head ----------------
__global__ void k_node_out(const float* __restrict__ agg2, const float* __restrict__ h1,
                           const float* __restrict__ Wl2, const float* __restrict__ bl2,
                           const float* __restrict__ Wr2, const float* __restrict__ Wse2,
                           const float* __restrict__ W3, const float* __restrict__ b3,
                           const float* __restrict__ W4, const float* __restrict__ b4,
                           const float* __restrict__ alpha_p,
                           float* __restrict__ out, int N) {
    __shared__ float sWl2[HID * HID], sWr2[HID * HID], sWse2[HID * HID], sW3[HID * HID];
    __shared__ float sbl2[HID], sb3[HID], sW4[HID];
    __shared__ float sb4, salpha;
    for (int i = threadIdx.x; i < HID * HID; i += blockDim.x) {
        sWl2[i] = Wl2[i]; sWr2[i] = Wr2[i]; sWse2[i] = Wse2[i]; sW3[i] = W3[i];
    }
    for (int i = threadIdx.x; i < HID; i += blockDim.x) { sbl2[i] = bl2[i]; sb3[i] = b3[i]; sW4[i] = W4[i]; }
    if (threadIdx.x == 0) { sb4 = b4[0]; salpha = alpha_p[0]; }
    __syncthreads();
    int i = blockIdx.x * blockDim.x + threadIdx.x;
    if (i >= N) return;
    float a[HID], hv[HID];
#pragma unroll
    for (int j = 0; j < HID; j += 4) {
        *(float4*)&a[j]  = *(const float4*)&agg2[(size_t)i * HID + j];
        *(float4*)&hv[j] = *(const float4*)&h1[(size_t)i * HID + j];
    }
    float h2[HID];
#pragma unroll
    for (int j = 0; j < HID; j++) {
        float acc = sbl2[j];
#pragma unroll
        for (int k = 0; k < HID; k++) acc += a[k] * sWl2[k * HID + j] + hv[k] * sWr2[k * HID + j];
        h2[j] = acc > 0.f ? acc : LEAKY * acc;
    }
    float skip[HID];
#pragma unroll
    for (int j = 0; j < HID; j++) {
        float acc = 0.f;
#pragma unroll
        for (int k = 0; k < HID; k++) acc += h2[k] * sWse2[k * HID + j];
        skip[j] = salpha * hv[j] + acc * SE3NORM;
    }
    float pred = sb4;
#pragma unroll
    for (int j = 0; j < HID; j++) {
        float acc = sb3[j];
#pragma unroll
        for (int k = 0; k < HID; k++) acc += skip[k] * sW3[k * HID + j];
        pred += (acc > 0.f ? acc : 0.f) * sW4[j];
    }
    out[i] = pred;
}

extern "C" void kernel_launch(void* const* d_in, const int* in_sizes, int n_in,
                              void* d_out, int out_size, void* d_ws, size_t ws_size,
                              hipStream_t stream) {
    const float* pos  = (const float*)d_in[0];
    const int*   ei   = (const int*)d_in[1];
    const float* Wl1  = (const float*)d_in[2];
    const float* bl1  = (const float*)d_in[3];
    const float* Wr1  = (const float*)d_in[4];
    const float* Wl2  = (const float*)d_in[5];
    const float* bl2  = (const float*)d_in[6];
    const float* Wr2  = (const float*)d_in[7];
    const float* Wse1 = (const float*)d_in[8];
    const float* Wse2 = (const float*)d_in[9];
    const float* W3   = (const float*)d_in[10];
    const float* b3   = (const float*)d_in[11];
    const float* W4   = (const float*)d_in[12];
    const float* b4   = (const float*)d_in[13];
    const float* alp  = (const float*)d_in[14];
    float* out = (float*)d_out;

    const int N = in_sizes[0] / 3;
    const int E = in_sizes[1] / 2;

    // workspace layout (fp32): [agg1: N*2][agg2: N*32][h1se: N*32]
    float* agg1 = (float*)d_ws;
    float* agg2 = agg1 + (size_t)2 * N;
    float* h1   = agg2 + (size_t)HID * N;

    // zero agg1 + agg2 (they are 0xAA-poisoned before every call)
    hipMemsetAsync(d_ws, 0, (size_t)(2 + HID) * N * sizeof(float), stream);

    const int blk = 256;
    k_edge_agg1<<<(E + blk - 1) / blk, blk, 0, stream>>>(ei, pos, agg1, E);
    k_node_h1<<<(N + blk - 1) / blk, blk, 0, stream>>>(agg1, pos, Wl1, bl1, Wr1, Wse1, h1, N);
    long long t2 = (long long)E * 8;
    k_edge_agg2<<<(int)((t2 + blk - 1) / blk), blk, 0, stream>>>(ei, h1, agg2, E);
    k_node_out<<<(N + blk - 1) / blk, blk, 0, stream>>>(agg2, h1, Wl2, bl2, Wr2, Wse2,
                                                        W3, b3, W4, b4, alp, out, N);
}

// Round 3
// 586.725 us; speedup vs baseline: 3.1617x; 3.1617x over previous
//
#include <hip/hip_runtime.h>

#define HID 32
#define LEAKY 0.01f
#define SE3NORM 0.17677669529663687f   // 1/sqrt(32)
#define SCAN_TILE 1024                 // elements per scan block (256 thr x 4)

// ---------------- histogram of dst ----------------
__global__ void k_hist(const int* __restrict__ ei, int* __restrict__ hist, int E) {
    int e = blockIdx.x * blockDim.x + threadIdx.x;
    if (e >= E) return;
    atomicAdd(&hist[ei[E + e]], 1);
}

// ---------------- scan pass 1: per-block exclusive scan + block sums ----------------
__global__ void k_scan1(const int* __restrict__ hist, int* __restrict__ scanned,
                        int* __restrict__ bsum, int M) {
    __shared__ int lds[256];
    int t = threadIdx.x;
    int base = blockIdx.x * SCAN_TILE + t * 4;
    int v0 = (base + 0 < M) ? hist[base + 0] : 0;
    int v1 = (base + 1 < M) ? hist[base + 1] : 0;
    int v2 = (base + 2 < M) ? hist[base + 2] : 0;
    int v3 = (base + 3 < M) ? hist[base + 3] : 0;
    int s = v0 + v1 + v2 + v3;
    lds[t] = s;
    __syncthreads();
    // Hillis-Steele inclusive scan over 256 thread sums
    for (int off = 1; off < 256; off <<= 1) {
        int x = (t >= off) ? lds[t - off] : 0;
        __syncthreads();
        lds[t] += x;
        __syncthreads();
    }
    int ex = lds[t] - s;  // exclusive prefix for this thread
    if (base + 0 < M) scanned[base + 0] = ex;
    if (base + 1 < M) scanned[base + 1] = ex + v0;
    if (base + 2 < M) scanned[base + 2] = ex + v0 + v1;
    if (base + 3 < M) scanned[base + 3] = ex + v0 + v1 + v2;
    if (t == 255) bsum[blockIdx.x] = lds[255];
}

// ---------------- scan pass 2: scan block sums (single block) ----------------
__global__ void k_scan2(int* __restrict__ bsum, int B) {
    __shared__ int lds[256];
    int t = threadIdx.x;
    int v = (t < B) ? bsum[t] : 0;
    lds[t] = v;
    __syncthreads();
    for (int off = 1; off < 256; off <<= 1) {
        int x = (t >= off) ? lds[t - off] : 0;
        __syncthreads();
        lds[t] += x;
        __syncthreads();
    }
    if (t < B) bsum[t] = lds[t] - v;  // exclusive
}

// ---------------- scan pass 3: combine, write offsets + cursor ----------------
__global__ void k_scan3(const int* __restrict__ scanned, const int* __restrict__ bsum,
                        int* __restrict__ offsets, int* __restrict__ cursor, int M, int N) {
    int i = blockIdx.x * blockDim.x + threadIdx.x;
    if (i >= M) return;
    int off = scanned[i] + bsum[i / SCAN_TILE];
    offsets[i] = off;
    if (i < N) cursor[i] = off;
}

// ---------------- scatter src into dst-sorted order ----------------
__global__ void k_scatter(const int* __restrict__ ei, int* __restrict__ cursor,
                          int* __restrict__ sorted_src, int E) {
    int e = blockIdx.x * blockDim.x + threadIdx.x;
    if (e >= E) return;
    int s = ei[e];
    int d = ei[E + e];
    int p = atomicAdd(&cursor[d], 1);
    sorted_src[p] = s;
}

// ------- fused layer 1: agg1 (segment sum) + h1 = leaky(agg1@Wl1+bl1+x@Wr1)@Wse1*SE3NORM -------
__global__ void k_node1(const int* __restrict__ offsets, const int* __restrict__ sorted_src,
                        const float* __restrict__ pos,
                        const float* __restrict__ Wl1, const float* __restrict__ bl1,
                        const float* __restrict__ Wr1, const float* __restrict__ Wse1,
                        float* __restrict__ h1out, int N) {
    __shared__ float sWl1[2 * HID], sWr1[2 * HID], sbl1[HID], sWse1[HID * HID];
    for (int i = threadIdx.x; i < 2 * HID; i += blockDim.x) { sWl1[i] = Wl1[i]; sWr1[i] = Wr1[i]; }
    for (int i = threadIdx.x; i < HID; i += blockDim.x) sbl1[i] = bl1[i];
    for (int i = threadIdx.x; i < HID * HID; i += blockDim.x) sWse1[i] = Wse1[i];
    __syncthreads();
    int i = blockIdx.x * blockDim.x + threadIdx.x;
    if (i >= N) return;
    int beg = offsets[i], end = offsets[i + 1];
    float a0 = 0.f, a1 = 0.f;
    for (int e = beg; e < end; e++) {
        int s = sorted_src[e];
        a0 += pos[s * 3 + 0];
        a1 += pos[s * 3 + 1];
    }
    float x0 = pos[3 * i], x1 = pos[3 * i + 1];
    float h[HID];
#pragma unroll
    for (int j = 0; j < HID; j++) {
        float v = a0 * sWl1[j] + a1 * sWl1[HID + j] + sbl1[j] + x0 * sWr1[j] + x1 * sWr1[HID + j];
        h[j] = v > 0.f ? v : LEAKY * v;
    }
#pragma unroll
    for (int c = 0; c < HID / 4; c++) {
        float4 o;
        float* op = (float*)&o;
#pragma unroll
        for (int jj = 0; jj < 4; jj++) {
            int j = c * 4 + jj;
            float acc = 0.f;
#pragma unroll
            for (int k = 0; k < HID; k++) acc += h[k] * sWse1[k * HID + j];
            op[jj] = acc * SE3NORM;
        }
        *(float4*)&h1out[(size_t)i * HID + c * 4] = o;
    }
}

// ------- fused layer 2 + head: agg2 segment-gather (8 thr/node) + conv2 + skip + MLP -> out -------
__global__ void k_node2out(const int* __restrict__ offsets, const int* __restrict__ sorted_src,
                           const float* __restrict__ h1,
                           const float* __restrict__ Wl2, const float* __restrict__ bl2,
                           const float* __restrict__ Wr2, const float* __restrict__ Wse2,
                           const float* __restrict__ W3, const float* __restrict__ b3,
                           const float* __restrict__ W4, const float* __restrict__ b4,
                           const float* __restrict__ alpha_p,
                           float* __restrict__ out, int N) {
    __shared__ float sWl2[HID * HID], sWr2[HID * HID], sWse2[HID * HID], sW3[HID * HID];
    __shared__ float sbl2[HID], sb3[HID], sW4[HID];
    __shared__ float sb4, salpha;
    __shared__ float sAgg[32][HID + 1], sH1[32][HID + 1], sH2[32][HID + 1], sSkip[32][HID + 1];
    for (int i = threadIdx.x; i < HID * HID; i += blockDim.x) {
        sWl2[i] = Wl2[i]; sWr2[i] = Wr2[i]; sWse2[i] = Wse2[i]; sW3[i] = W3[i];
    }
    for (int i = threadIdx.x; i < HID; i += blockDim.x) { sbl2[i] = bl2[i]; sb3[i] = b3[i]; sW4[i] = W4[i]; }
    if (threadIdx.x == 0) { sb4 = b4[0]; salpha = alpha_p[0]; }
    __syncthreads();

    const int lt = threadIdx.x;       // 0..255
    const int nodeL = lt >> 3;        // 0..31 local node
    const int t = lt & 7;             // feature chunk (4 floats)
    const int node = blockIdx.x * 32 + nodeL;
    const bool live = node < N;

    // phase 1: segment-sum gather of h1[src] (no atomics), plus own h1
    if (live) {
        int beg = offsets[node], end = offsets[node + 1];
        float4 acc = make_float4(0.f, 0.f, 0.f, 0.f);
        for (int e = beg; e < end; e++) {
            int s = sorted_src[e];
            float4 v = *(const float4*)&h1[(size_t)s * HID + t * 4];
            acc.x += v.x; acc.y += v.y; acc.z += v.z; acc.w += v.w;
        }
        float4 hv = *(const float4*)&h1[(size_t)node * HID + t * 4];
        sAgg[nodeL][t * 4 + 0] = acc.x; sAgg[nodeL][t * 4 + 1] = acc.y;
        sAgg[nodeL][t * 4 + 2] = acc.z; sAgg[nodeL][t * 4 + 3] = acc.w;
        sH1[nodeL][t * 4 + 0] = hv.x; sH1[nodeL][t * 4 + 1] = hv.y;
        sH1[nodeL][t * 4 + 2] = hv.z; sH1[nodeL][t * 4 + 3] = hv.w;
    }
    __syncthreads();

    // phase 2: h2 = leaky(agg2@Wl2 + bl2 + h1@Wr2) -- each thread does 4 features
    if (live) {
#pragma unroll
        for (int jj = 0; jj < 4; jj++) {
            int j = t * 4 + jj;
            float acc = sbl2[j];
#pragma unroll
            for (int k = 0; k < HID; k++)
                acc += sAgg[nodeL][k] * sWl2[k * HID + j] + sH1[nodeL][k] * sWr2[k * HID + j];
            sH2[nodeL][j] = acc > 0.f ? acc : LEAKY * acc;
        }
    }
    __syncthreads();

    // phase 3: skip = alpha*h1 + (h2@Wse2)*SE3NORM
    if (live) {
#pragma unroll
        for (int jj = 0; jj < 4; jj++) {
            int j = t * 4 + jj;
            float acc = 0.f;
#pragma unroll
            for (int k = 0; k < HID; k++) acc += sH2[nodeL][k] * sWse2[k * HID + j];
            sSkip[nodeL][j] = salpha * sH1[nodeL][j] + acc * SE3NORM;
        }
    }
    __syncthreads();

    // phase 4: pred = b4 + sum_j relu(skip@W3 + b3)_j * W4_j  (partial over 4 j's, shfl-reduce 8 lanes)
    float part = 0.f;
#pragma unroll
    for (int jj = 0; jj < 4; jj++) {
        int j = t * 4 + jj;
        float acc = sb3[j];
        if (live) {
#pragma unroll
            for (int k = 0; k < HID; k++) acc += sSkip[nodeL][k] * sW3[k * HID + j];
        }
        part += (acc > 0.f ? acc : 0.f) * sW4[j];
    }
    part += __shfl_xor(part, 1);
    part += __shfl_xor(part, 2);
    part += __shfl_xor(part, 4);
    if (live && t == 0) out[node] = part + sb4;
}

extern "C" void kernel_launch(void* const* d_in, const int* in_sizes, int n_in,
                              void* d_out, int out_size, void* d_ws, size_t ws_size,
                              hipStream_t stream) {
    const float* pos  = (const float*)d_in[0];
    const int*   ei   = (const int*)d_in[1];
    const float* Wl1  = (const float*)d_in[2];
    const float* bl1  = (const float*)d_in[3];
    const float* Wr1  = (const float*)d_in[4];
    const float* Wl2  = (const float*)d_in[5];
    const float* bl2  = (const float*)d_in[6];
    const float* Wr2  = (const float*)d_in[7];
    const float* Wse1 = (const float*)d_in[8];
    const float* Wse2 = (const float*)d_in[9];
    const float* W3   = (const float*)d_in[10];
    const float* b3   = (const float*)d_in[11];
    const float* W4   = (const float*)d_in[12];
    const float* b4   = (const float*)d_in[13];
    const float* alp  = (const float*)d_in[14];
    float* out = (float*)d_out;

    const int N = in_sizes[0] / 3;
    const int E = in_sizes[1] / 2;
    const int M = N + 1;                       // hist padded with one zero for offsets[N]=E
    const int B = (M + SCAN_TILE - 1) / SCAN_TILE;

    // workspace layout (ints): hist[M] scanned[M] offsets[M] cursor[N] bsum[256] sorted_src[E] | h1 (fp32, 16B-aligned)
    int* hist       = (int*)d_ws;
    int* scanned    = hist + M;
    int* offsets    = scanned + M;
    int* cursor     = offsets + M;
    int* bsum       = cursor + N;
    int* sorted_src = bsum + 256;
    uintptr_t hp = (uintptr_t)(sorted_src + E);
    hp = (hp + 15) & ~(uintptr_t)15;
    float* h1 = (float*)hp;

    hipMemsetAsync(hist, 0, (size_t)M * sizeof(int), stream);

    const int blk = 256;
    k_hist<<<(E + blk - 1) / blk, blk, 0, stream>>>(ei, hist, E);
    k_scan1<<<B, 256, 0, stream>>>(hist, scanned, bsum, M);
    k_scan2<<<1, 256, 0, stream>>>(bsum, B);
    k_scan3<<<(M + blk - 1) / blk, blk, 0, stream>>>(scanned, bsum, offsets, cursor, M, N);
    k_scatter<<<(E + blk - 1) / blk, blk, 0, stream>>>(ei, cursor, sorted_src, E);
    k_node1<<<(N + blk - 1) / blk, blk, 0, stream>>>(offsets, sorted_src, pos, Wl1, bl1, Wr1, Wse1, h1, N);
    k_node2out<<<(N + 31) / 32, 256, 0, stream>>>(offsets, sorted_src, h1, Wl2, bl2, Wr2, Wse2,
                                                  W3, b3, W4, b4, alp, out, N);
}

// Round 4
// 429.053 us; speedup vs baseline: 4.3236x; 1.3675x over previous
//
#include <hip/hip_runtime.h>

#define HID 32
#define LEAKY 0.01f
#define SE3NORM 0.17677669529663687f   // 1/sqrt(32)
#define SCAN_TILE 1024                 // elements per scan block (256 thr x 4)

// ---------------- pass 1a: histogram of dst + per-edge rank ----------------
__global__ void k_hist_rank(const int* __restrict__ ei, int* __restrict__ hist,
                            int* __restrict__ rank, int E) {
    int base = (blockIdx.x * blockDim.x + threadIdx.x) * 4;
#pragma unroll
    for (int u = 0; u < 4; u++) {
        int e = base + u;
        if (e < E) rank[e] = atomicAdd(&hist[ei[E + e]], 1);
    }
}

// ---------------- pass 1b (fallback, no rank array): histogram only ----------------
__global__ void k_hist(const int* __restrict__ ei, int* __restrict__ hist, int E) {
    int base = (blockIdx.x * blockDim.x + threadIdx.x) * 4;
#pragma unroll
    for (int u = 0; u < 4; u++) {
        int e = base + u;
        if (e < E) atomicAdd(&hist[ei[E + e]], 1);
    }
}

// ---------------- scan pass 1: per-block exclusive scan (into offsets) + block sums ----------------
__global__ void k_scan1(const int* __restrict__ hist, int* __restrict__ offsets,
                        int* __restrict__ bsum, int M) {
    __shared__ int lds[256];
    int t = threadIdx.x;
    int base = blockIdx.x * SCAN_TILE + t * 4;
    int v0 = (base + 0 < M) ? hist[base + 0] : 0;
    int v1 = (base + 1 < M) ? hist[base + 1] : 0;
    int v2 = (base + 2 < M) ? hist[base + 2] : 0;
    int v3 = (base + 3 < M) ? hist[base + 3] : 0;
    int s = v0 + v1 + v2 + v3;
    lds[t] = s;
    __syncthreads();
    for (int off = 1; off < 256; off <<= 1) {
        int x = (t >= off) ? lds[t - off] : 0;
        __syncthreads();
        lds[t] += x;
        __syncthreads();
    }
    int ex = lds[t] - s;
    if (base + 0 < M) offsets[base + 0] = ex;
    if (base + 1 < M) offsets[base + 1] = ex + v0;
    if (base + 2 < M) offsets[base + 2] = ex + v0 + v1;
    if (base + 3 < M) offsets[base + 3] = ex + v0 + v1 + v2;
    if (t == 255) bsum[blockIdx.x] = lds[255];
}

// ---------------- scan pass 2: scan block sums (single block) ----------------
__global__ void k_scan2(int* __restrict__ bsum, int B) {
    __shared__ int lds[256];
    int t = threadIdx.x;
    int v = (t < B) ? bsum[t] : 0;
    lds[t] = v;
    __syncthreads();
    for (int off = 1; off < 256; off <<= 1) {
        int x = (t >= off) ? lds[t - off] : 0;
        __syncthreads();
        lds[t] += x;
        __syncthreads();
    }
    if (t < B) bsum[t] = lds[t] - v;  // exclusive
}

// ---------------- scan pass 3: add block prefix; optionally init cursor ----------------
__global__ void k_scan3(int* __restrict__ offsets, const int* __restrict__ bsum,
                        int* __restrict__ cursor, int M, int N) {
    int i = blockIdx.x * blockDim.x + threadIdx.x;
    if (i >= M) return;
    int off = offsets[i] + bsum[i / SCAN_TILE];
    offsets[i] = off;
    if (cursor && i < N) cursor[i] = off;
}

// ---------------- pass 2a: atomic-free scatter via precomputed ranks ----------------
__global__ void k_scatter_rank(const int* __restrict__ ei, const int* __restrict__ offsets,
                               const int* __restrict__ rank, int* __restrict__ sorted_src, int E) {
    int base = (blockIdx.x * blockDim.x + threadIdx.x) * 4;
#pragma unroll
    for (int u = 0; u < 4; u++) {
        int e = base + u;
        if (e < E) {
            int d = ei[E + e];
            sorted_src[offsets[d] + rank[e]] = ei[e];
        }
    }
}

// ---------------- pass 2b (fallback): scatter with atomic cursor ----------------
__global__ void k_scatter_atomic(const int* __restrict__ ei, int* __restrict__ cursor,
                                 int* __restrict__ sorted_src, int E) {
    int base = (blockIdx.x * blockDim.x + threadIdx.x) * 4;
#pragma unroll
    for (int u = 0; u < 4; u++) {
        int e = base + u;
        if (e < E) {
            int p = atomicAdd(&cursor[ei[E + e]], 1);
            sorted_src[p] = ei[e];
        }
    }
}

// ------- fused layer 1: agg1 (segment sum) + h1 = leaky(agg1@Wl1+bl1+x@Wr1)@Wse1*SE3NORM -------
__global__ void k_node1(const int* __restrict__ offsets, const int* __restrict__ sorted_src,
                        const float* __restrict__ pos,
                        const float* __restrict__ Wl1, const float* __restrict__ bl1,
                        const float* __restrict__ Wr1, const float* __restrict__ Wse1,
                        float* __restrict__ h1out, int N) {
    __shared__ float sWl1[2 * HID], sWr1[2 * HID], sbl1[HID], sWse1[HID * HID];
    for (int i = threadIdx.x; i < 2 * HID; i += blockDim.x) { sWl1[i] = Wl1[i]; sWr1[i] = Wr1[i]; }
    for (int i = threadIdx.x; i < HID; i += blockDim.x) sbl1[i] = bl1[i];
    for (int i = threadIdx.x; i < HID * HID; i += blockDim.x) sWse1[i] = Wse1[i];
    __syncthreads();
    int i = blockIdx.x * blockDim.x + threadIdx.x;
    if (i >= N) return;
    int beg = offsets[i], end = offsets[i + 1];
    float a0 = 0.f, a1 = 0.f;
    int e = beg;
    for (; e + 4 <= end; e += 4) {
        int s0 = sorted_src[e], s1 = sorted_src[e + 1], s2 = sorted_src[e + 2], s3 = sorted_src[e + 3];
        a0 += pos[s0 * 3] + pos[s1 * 3] + pos[s2 * 3] + pos[s3 * 3];
        a1 += pos[s0 * 3 + 1] + pos[s1 * 3 + 1] + pos[s2 * 3 + 1] + pos[s3 * 3 + 1];
    }
    for (; e < end; e++) {
        int s = sorted_src[e];
        a0 += pos[s * 3];
        a1 += pos[s * 3 + 1];
    }
    float x0 = pos[3 * i], x1 = pos[3 * i + 1];
    float h[HID];
#pragma unroll
    for (int j = 0; j < HID; j++) {
        float v = a0 * sWl1[j] + a1 * sWl1[HID + j] + sbl1[j] + x0 * sWr1[j] + x1 * sWr1[HID + j];
        h[j] = v > 0.f ? v : LEAKY * v;
    }
#pragma unroll
    for (int c = 0; c < HID / 4; c++) {
        float4 o;
        float* op = (float*)&o;
#pragma unroll
        for (int jj = 0; jj < 4; jj++) {
            int j = c * 4 + jj;
            float acc = 0.f;
#pragma unroll
            for (int k = 0; k < HID; k++) acc += h[k] * sWse1[k * HID + j];
            op[jj] = acc * SE3NORM;
        }
        *(float4*)&h1out[(size_t)i * HID + c * 4] = o;
    }
}

// ------- fused layer 2 + head: agg2 segment-gather (8 thr/node) + conv2 + skip + MLP -> out -------
__global__ void k_node2out(const int* __restrict__ offsets, const int* __restrict__ sorted_src,
                           const float* __restrict__ h1,
                           const float* __restrict__ Wl2, const float* __restrict__ bl2,
                           const float* __restrict__ Wr2, const float* __restrict__ Wse2,
                           const float* __restrict__ W3, const float* __restrict__ b3,
                           const float* __restrict__ W4, const float* __restrict__ b4,
                           const float* __restrict__ alpha_p,
                           float* __restrict__ out, int N) {
    __shared__ float sWl2[HID * HID], sWr2[HID * HID], sWse2[HID * HID], sW3[HID * HID];
    __shared__ float sbl2[HID], sb3[HID], sW4[HID];
    __shared__ float sb4, salpha;
    __shared__ float sAgg[32][HID + 1], sH1[32][HID + 1], sH2[32][HID + 1], sSkip[32][HID + 1];
    for (int i = threadIdx.x; i < HID * HID; i += blockDim.x) {
        sWl2[i] = Wl2[i]; sWr2[i] = Wr2[i]; sWse2[i] = Wse2[i]; sW3[i] = W3[i];
    }
    for (int i = threadIdx.x; i < HID; i += blockDim.x) { sbl2[i] = bl2[i]; sb3[i] = b3[i]; sW4[i] = W4[i]; }
    if (threadIdx.x == 0) { sb4 = b4[0]; salpha = alpha_p[0]; }
    __syncthreads();

    const int lt = threadIdx.x;       // 0..255
    const int nodeL = lt >> 3;        // 0..31 local node
    const int t = lt & 7;             // feature chunk (4 floats)
    const int node = blockIdx.x * 32 + nodeL;
    const bool live = node < N;

    // phase 1: segment-sum gather of h1[src] (no atomics), 4-way unrolled
    if (live) {
        int beg = offsets[node], end = offsets[node + 1];
        float4 acc = make_float4(0.f, 0.f, 0.f, 0.f);
        int e = beg;
        for (; e + 4 <= end; e += 4) {
            int s0 = sorted_src[e], s1 = sorted_src[e + 1];
            int s2 = sorted_src[e + 2], s3 = sorted_src[e + 3];
            float4 v0 = *(const float4*)&h1[(size_t)s0 * HID + t * 4];
            float4 v1 = *(const float4*)&h1[(size_t)s1 * HID + t * 4];
            float4 v2 = *(const float4*)&h1[(size_t)s2 * HID + t * 4];
            float4 v3 = *(const float4*)&h1[(size_t)s3 * HID + t * 4];
            acc.x += v0.x + v1.x + v2.x + v3.x;
            acc.y += v0.y + v1.y + v2.y + v3.y;
            acc.z += v0.z + v1.z + v2.z + v3.z;
            acc.w += v0.w + v1.w + v2.w + v3.w;
        }
        for (; e < end; e++) {
            int s = sorted_src[e];
            float4 v = *(const float4*)&h1[(size_t)s * HID + t * 4];
            acc.x += v.x; acc.y += v.y; acc.z += v.z; acc.w += v.w;
        }
        float4 hv = *(const float4*)&h1[(size_t)node * HID + t * 4];
        sAgg[nodeL][t * 4 + 0] = acc.x; sAgg[nodeL][t * 4 + 1] = acc.y;
        sAgg[nodeL][t * 4 + 2] = acc.z; sAgg[nodeL][t * 4 + 3] = acc.w;
        sH1[nodeL][t * 4 + 0] = hv.x; sH1[nodeL][t * 4 + 1] = hv.y;
        sH1[nodeL][t * 4 + 2] = hv.z; sH1[nodeL][t * 4 + 3] = hv.w;
    }
    __syncthreads();

    // phase 2: h2 = leaky(agg2@Wl2 + bl2 + h1@Wr2)
    if (live) {
#pragma unroll
        for (int jj = 0; jj < 4; jj++) {
            int j = t * 4 + jj;
            float acc = sbl2[j];
#pragma unroll
            for (int k = 0; k < HID; k++)
                acc += sAgg[nodeL][k] * sWl2[k * HID + j] + sH1[nodeL][k] * sWr2[k * HID + j];
            sH2[nodeL][j] = acc > 0.f ? acc : LEAKY * acc;
        }
    }
    __syncthreads();

    // phase 3: skip = alpha*h1 + (h2@Wse2)*SE3NORM
    if (live) {
#pragma unroll
        for (int jj = 0; jj < 4; jj++) {
            int j = t * 4 + jj;
            float acc = 0.f;
#pragma unroll
            for (int k = 0; k < HID; k++) acc += sH2[nodeL][k] * sWse2[k * HID + j];
            sSkip[nodeL][j] = salpha * sH1[nodeL][j] + acc * SE3NORM;
        }
    }
    __syncthreads();

    // phase 4: pred = b4 + sum_j relu(skip@W3 + b3)_j * W4_j  (shfl-reduce 8 lanes)
    float part = 0.f;
#pragma unroll
    for (int jj = 0; jj < 4; jj++) {
        int j = t * 4 + jj;
        float acc = sb3[j];
        if (live) {
#pragma unroll
            for (int k = 0; k < HID; k++) acc += sSkip[nodeL][k] * sW3[k * HID + j];
        }
        part += (acc > 0.f ? acc : 0.f) * sW4[j];
    }
    part += __shfl_xor(part, 1);
    part += __shfl_xor(part, 2);
    part += __shfl_xor(part, 4);
    if (live && t == 0) out[node] = part + sb4;
}

extern "C" void kernel_launch(void* const* d_in, const int* in_sizes, int n_in,
                              void* d_out, int out_size, void* d_ws, size_t ws_size,
                              hipStream_t stream) {
    const float* pos  = (const float*)d_in[0];
    const int*   ei   = (const int*)d_in[1];
    const float* Wl1  = (const float*)d_in[2];
    const float* bl1  = (const float*)d_in[3];
    const float* Wr1  = (const float*)d_in[4];
    const float* Wl2  = (const float*)d_in[5];
    const float* bl2  = (const float*)d_in[6];
    const float* Wr2  = (const float*)d_in[7];
    const float* Wse1 = (const float*)d_in[8];
    const float* Wse2 = (const float*)d_in[9];
    const float* W3   = (const float*)d_in[10];
    const float* b3   = (const float*)d_in[11];
    const float* W4   = (const float*)d_in[12];
    const float* b4   = (const float*)d_in[13];
    const float* alp  = (const float*)d_in[14];
    float* out = (float*)d_out;

    const int N = in_sizes[0] / 3;
    const int E = in_sizes[1] / 2;
    const int M = N + 1;                       // offsets[N] = E
    const int B = (M + SCAN_TILE - 1) / SCAN_TILE;

    // workspace: hist[M] offsets[M] bsum[256] sorted_src[E] aux[E or N] | h1[32N] (16B aligned)
    int* hist       = (int*)d_ws;
    int* offsets    = hist + M;
    int* bsum       = offsets + M;
    int* sorted_src = bsum + 256;
    int* aux        = sorted_src + E;          // rank[E] (scheme A) or cursor[N] (scheme B)

    uintptr_t hpA = ((uintptr_t)(aux + E) + 15) & ~(uintptr_t)15;
    uintptr_t hpB = ((uintptr_t)(aux + N) + 15) & ~(uintptr_t)15;
    size_t needA = (hpA - (uintptr_t)d_ws) + (size_t)HID * N * sizeof(float);
    const bool useRank = (needA <= ws_size);   // call-invariant -> graph-safe branch
    float* h1 = (float*)(useRank ? hpA : hpB);

    hipMemsetAsync(hist, 0, (size_t)M * sizeof(int), stream);

    const int blk = 256;
    const int egrid4 = (E / 4 + blk) / blk;    // threads cover ceil(E/4), each does 4 edges

    if (useRank) {
        k_hist_rank<<<egrid4, blk, 0, stream>>>(ei, hist, aux, E);
        k_scan1<<<B, 256, 0, stream>>>(hist, offsets, bsum, M);
        k_scan2<<<1, 256, 0, stream>>>(bsum, B);
        k_scan3<<<(M + blk - 1) / blk, blk, 0, stream>>>(offsets, bsum, nullptr, M, N);
        k_scatter_rank<<<egrid4, blk, 0, stream>>>(ei, offsets, aux, sorted_src, E);
    } else {
        k_hist<<<egrid4, blk, 0, stream>>>(ei, hist, E);
        k_scan1<<<B, 256, 0, stream>>>(hist, offsets, bsum, M);
        k_scan2<<<1, 256, 0, stream>>>(bsum, B);
        k_scan3<<<(M + blk - 1) / blk, blk, 0, stream>>>(offsets, bsum, aux, M, N);
        k_scatter_atomic<<<egrid4, blk, 0, stream>>>(ei, aux, sorted_src, E);
    }
    k_node1<<<(N + blk - 1) / blk, blk, 0, stream>>>(offsets, sorted_src, pos, Wl1, bl1, Wr1, Wse1, h1, N);
    k_node2out<<<(N + 31) / 32, 256, 0, stream>>>(offsets, sorted_src, h1, Wl2, bl2, Wr2, Wse2,
                                                  W3, b3, W4, b4, alp, out, N);
}

// Round 5
// 290.877 us; speedup vs baseline: 6.3774x; 1.4750x over previous
//
#include <hip/hip_runtime.h>

#define HID 32
#define LEAKY 0.01f
#define SE3NORM 0.17677669529663687f   // 1/sqrt(32)
#define SCAN_TILE 1024                 // elements per scan block (256 thr x 4)
#define NBK 128                        // nodes per fine bucket
#define GA 256                         // pass-A blocks

// ======================= two-level bucket CSR build (no global atomics) =======================

// pass A1: per-block LDS histogram of coarse bucket (dst>>7); bh[b*GA + g] = count
__global__ void k_bhist(const int* __restrict__ ei, int* __restrict__ bh,
                        int E, int B1, int chunk) {
    extern __shared__ int lh[];                 // B1 ints
    int g = blockIdx.x;
    for (int i = threadIdx.x; i < B1; i += 256) lh[i] = 0;
    __syncthreads();
    int beg = g * chunk, end = min(E, beg + chunk);
    for (int e = beg + (int)threadIdx.x; e < end; e += 256)
        atomicAdd(&lh[ei[E + e] >> 7], 1);
    __syncthreads();
    for (int b = threadIdx.x; b < B1; b += 256) bh[b * GA + g] = lh[b];
}

// scan pass 1: per-tile exclusive scan IN PLACE + tile sums
__global__ void k_scan1(int* __restrict__ data, int* __restrict__ bsum, int M) {
    __shared__ int lds[256];
    int t = threadIdx.x;
    int base = blockIdx.x * SCAN_TILE + t * 4;
    int v0 = (base + 0 < M) ? data[base + 0] : 0;
    int v1 = (base + 1 < M) ? data[base + 1] : 0;
    int v2 = (base + 2 < M) ? data[base + 2] : 0;
    int v3 = (base + 3 < M) ? data[base + 3] : 0;
    int s = v0 + v1 + v2 + v3;
    lds[t] = s;
    __syncthreads();
    for (int off = 1; off < 256; off <<= 1) {
        int x = (t >= off) ? lds[t - off] : 0;
        __syncthreads();
        lds[t] += x;
        __syncthreads();
    }
    int ex = lds[t] - s;
    if (base + 0 < M) data[base + 0] = ex;
    if (base + 1 < M) data[base + 1] = ex + v0;
    if (base + 2 < M) data[base + 2] = ex + v0 + v1;
    if (base + 3 < M) data[base + 3] = ex + v0 + v1 + v2;
    if (t == 255) bsum[blockIdx.x] = lds[255];
}

// scan pass 2: exclusive scan of tile sums (single block, B<=256)
__global__ void k_scan2(int* __restrict__ bsum, int B) {
    __shared__ int lds[256];
    int t = threadIdx.x;
    int v = (t < B) ? bsum[t] : 0;
    lds[t] = v;
    __syncthreads();
    for (int off = 1; off < 256; off <<= 1) {
        int x = (t >= off) ? lds[t - off] : 0;
        __syncthreads();
        lds[t] += x;
        __syncthreads();
    }
    if (t < B) bsum[t] = lds[t] - v;
}

// scan pass 3: add tile prefix in place; optionally init cursor copy
__global__ void k_scan3(int* __restrict__ data, const int* __restrict__ bsum,
                        int* __restrict__ cursor, int M, int N) {
    int i = blockIdx.x * blockDim.x + threadIdx.x;
    if (i >= M) return;
    int off = data[i] + bsum[i / SCAN_TILE];
    data[i] = off;
    if (cursor && i < N) cursor[i] = off;
}

// pass A3: scatter edges into coarse buckets via LDS cursors; pack (localdst<<24)|src
__global__ void k_bscatter(const int* __restrict__ ei, const int* __restrict__ bh,
                           int* __restrict__ bucketed, int E, int B1, int chunk) {
    extern __shared__ int cur[];                // B1 ints
    int g = blockIdx.x;
    for (int b = threadIdx.x; b < B1; b += 256) cur[b] = bh[b * GA + g];
    __syncthreads();
    int beg = g * chunk, end = min(E, beg + chunk);
    for (int e = beg + (int)threadIdx.x; e < end; e += 256) {
        int d = ei[E + e];
        int s = ei[e];
        int b = d >> 7;
        int p = atomicAdd(&cur[b], 1);          // LDS atomic; slices disjoint per (b,g)
        bucketed[p] = s | ((d & (NBK - 1)) << 24);
    }
}

// pass B: per-bucket LDS counting sort -> sorted_src + offsets
__global__ void k_bsort(const int* __restrict__ bh, const int* __restrict__ bucketed,
                        int* __restrict__ sorted_src, int* __restrict__ offsets,
                        int E, int N, int B1) {
    __shared__ int hist[NBK], sc[NBK], base[NBK];
    int b = blockIdx.x;
    int t = threadIdx.x;
    int bs = bh[b * GA];
    int be = (b == B1 - 1) ? E : bh[(b + 1) * GA];
    if (t < NBK) hist[t] = 0;
    __syncthreads();
    for (int e = bs + t; e < be; e += 256)
        atomicAdd(&hist[bucketed[e] >> 24], 1);
    __syncthreads();
    int v = (t < NBK) ? hist[t] : 0;
    if (t < NBK) sc[t] = v;
    __syncthreads();
    for (int off = 1; off < NBK; off <<= 1) {
        int x = (t < NBK && t >= off) ? sc[t - off] : 0;
        __syncthreads();
        if (t < NBK) sc[t] += x;
        __syncthreads();
    }
    if (t < NBK) base[t] = sc[t] - v;           // exclusive
    __syncthreads();
    if (t < NBK) hist[t] = base[t];             // reuse hist as cursor
    __syncthreads();
    for (int e = bs + t; e < be; e += 256) {
        int pv = bucketed[e];
        int p = atomicAdd(&hist[pv >> 24], 1);
        sorted_src[bs + p] = pv & 0x00FFFFFF;
    }
    int node = b * NBK + t;
    if (t < NBK && node < N) offsets[node] = bs + base[t];
    if (b == B1 - 1 && t == 0) offsets[N] = E;
}

// ======================= fallback CSR build (global atomics, R4 path) =======================
__global__ void k_hist_rank(const int* __restrict__ ei, int* __restrict__ hist,
                            int* __restrict__ rank, int E) {
    int base = (blockIdx.x * blockDim.x + threadIdx.x) * 4;
#pragma unroll
    for (int u = 0; u < 4; u++) {
        int e = base + u;
        if (e < E) rank[e] = atomicAdd(&hist[ei[E + e]], 1);
    }
}
__global__ void k_hist(const int* __restrict__ ei, int* __restrict__ hist, int E) {
    int base = (blockIdx.x * blockDim.x + threadIdx.x) * 4;
#pragma unroll
    for (int u = 0; u < 4; u++) {
        int e = base + u;
        if (e < E) atomicAdd(&hist[ei[E + e]], 1);
    }
}
__global__ void k_scatter_rank(const int* __restrict__ ei, const int* __restrict__ offsets,
                               const int* __restrict__ rank, int* __restrict__ sorted_src, int E) {
    int base = (blockIdx.x * blockDim.x + threadIdx.x) * 4;
#pragma unroll
    for (int u = 0; u < 4; u++) {
        int e = base + u;
        if (e < E) sorted_src[offsets[ei[E + e]] + rank[e]] = ei[e];
    }
}
__global__ void k_scatter_atomic(const int* __restrict__ ei, int* __restrict__ cursor,
                                 int* __restrict__ sorted_src, int E) {
    int base = (blockIdx.x * blockDim.x + threadIdx.x) * 4;
#pragma unroll
    for (int u = 0; u < 4; u++) {
        int e = base + u;
        if (e < E) {
            int p = atomicAdd(&cursor[ei[E + e]], 1);
            sorted_src[p] = ei[e];
        }
    }
}

// ======================= node-level fused kernels =======================
__global__ void k_node1(const int* __restrict__ offsets, const int* __restrict__ sorted_src,
                        const float* __restrict__ pos,
                        const float* __restrict__ Wl1, const float* __restrict__ bl1,
                        const float* __restrict__ Wr1, const float* __restrict__ Wse1,
                        float* __restrict__ h1out, int N) {
    __shared__ float sWl1[2 * HID], sWr1[2 * HID], sbl1[HID], sWse1[HID * HID];
    for (int i = threadIdx.x; i < 2 * HID; i += blockDim.x) { sWl1[i] = Wl1[i]; sWr1[i] = Wr1[i]; }
    for (int i = threadIdx.x; i < HID; i += blockDim.x) sbl1[i] = bl1[i];
    for (int i = threadIdx.x; i < HID * HID; i += blockDim.x) sWse1[i] = Wse1[i];
    __syncthreads();
    int i = blockIdx.x * blockDim.x + threadIdx.x;
    if (i >= N) return;
    int beg = offsets[i], end = offsets[i + 1];
    float a0 = 0.f, a1 = 0.f;
    int e = beg;
    for (; e + 4 <= end; e += 4) {
        int s0 = sorted_src[e], s1 = sorted_src[e + 1], s2 = sorted_src[e + 2], s3 = sorted_src[e + 3];
        a0 += pos[s0 * 3] + pos[s1 * 3] + pos[s2 * 3] + pos[s3 * 3];
        a1 += pos[s0 * 3 + 1] + pos[s1 * 3 + 1] + pos[s2 * 3 + 1] + pos[s3 * 3 + 1];
    }
    for (; e < end; e++) {
        int s = sorted_src[e];
        a0 += pos[s * 3];
        a1 += pos[s * 3 + 1];
    }
    float x0 = pos[3 * i], x1 = pos[3 * i + 1];
    float h[HID];
#pragma unroll
    for (int j = 0; j < HID; j++) {
        float v = a0 * sWl1[j] + a1 * sWl1[HID + j] + sbl1[j] + x0 * sWr1[j] + x1 * sWr1[HID + j];
        h[j] = v > 0.f ? v : LEAKY * v;
    }
#pragma unroll
    for (int c = 0; c < HID / 4; c++) {
        float4 o;
        float* op = (float*)&o;
#pragma unroll
        for (int jj = 0; jj < 4; jj++) {
            int j = c * 4 + jj;
            float acc = 0.f;
#pragma unroll
            for (int k = 0; k < HID; k++) acc += h[k] * sWse1[k * HID + j];
            op[jj] = acc * SE3NORM;
        }
        *(float4*)&h1out[(size_t)i * HID + c * 4] = o;
    }
}

__global__ void k_node2out(const int* __restrict__ offsets, const int* __restrict__ sorted_src,
                           const float* __restrict__ h1,
                           const float* __restrict__ Wl2, const float* __restrict__ bl2,
                           const float* __restrict__ Wr2, const float* __restrict__ Wse2,
                           const float* __restrict__ W3, const float* __restrict__ b3,
                           const float* __restrict__ W4, const float* __restrict__ b4,
                           const float* __restrict__ alpha_p,
                           float* __restrict__ out, int N) {
    __shared__ float sWl2[HID * HID], sWr2[HID * HID], sWse2[HID * HID], sW3[HID * HID];
    __shared__ float sbl2[HID], sb3[HID], sW4[HID];
    __shared__ float sb4, salpha;
    __shared__ float sAgg[32][HID + 1], sH1[32][HID + 1], sH2[32][HID + 1], sSkip[32][HID + 1];
    for (int i = threadIdx.x; i < HID * HID; i += blockDim.x) {
        sWl2[i] = Wl2[i]; sWr2[i] = Wr2[i]; sWse2[i] = Wse2[i]; sW3[i] = W3[i];
    }
    for (int i = threadIdx.x; i < HID; i += blockDim.x) { sbl2[i] = bl2[i]; sb3[i] = b3[i]; sW4[i] = W4[i]; }
    if (threadIdx.x == 0) { sb4 = b4[0]; salpha = alpha_p[0]; }
    __syncthreads();

    const int lt = threadIdx.x;
    const int nodeL = lt >> 3;
    const int t = lt & 7;
    const int node = blockIdx.x * 32 + nodeL;
    const bool live = node < N;

    if (live) {
        int beg = offsets[node], end = offsets[node + 1];
        float4 acc = make_float4(0.f, 0.f, 0.f, 0.f);
        int e = beg;
        for (; e + 4 <= end; e += 4) {
            int s0 = sorted_src[e], s1 = sorted_src[e + 1];
            int s2 = sorted_src[e + 2], s3 = sorted_src[e + 3];
            float4 v0 = *(const float4*)&h1[(size_t)s0 * HID + t * 4];
            float4 v1 = *(const float4*)&h1[(size_t)s1 * HID + t * 4];
            float4 v2 = *(const float4*)&h1[(size_t)s2 * HID + t * 4];
            float4 v3 = *(const float4*)&h1[(size_t)s3 * HID + t * 4];
            acc.x += v0.x + v1.x + v2.x + v3.x;
            acc.y += v0.y + v1.y + v2.y + v3.y;
            acc.z += v0.z + v1.z + v2.z + v3.z;
            acc.w += v0.w + v1.w + v2.w + v3.w;
        }
        for (; e < end; e++) {
            int s = sorted_src[e];
            float4 v = *(const float4*)&h1[(size_t)s * HID + t * 4];
            acc.x += v.x; acc.y += v.y; acc.z += v.z; acc.w += v.w;
        }
        float4 hv = *(const float4*)&h1[(size_t)node * HID + t * 4];
        sAgg[nodeL][t * 4 + 0] = acc.x; sAgg[nodeL][t * 4 + 1] = acc.y;
        sAgg[nodeL][t * 4 + 2] = acc.z; sAgg[nodeL][t * 4 + 3] = acc.w;
        sH1[nodeL][t * 4 + 0] = hv.x; sH1[nodeL][t * 4 + 1] = hv.y;
        sH1[nodeL][t * 4 + 2] = hv.z; sH1[nodeL][t * 4 + 3] = hv.w;
    }
    __syncthreads();

    if (live) {
#pragma unroll
        for (int jj = 0; jj < 4; jj++) {
            int j = t * 4 + jj;
            float acc = sbl2[j];
#pragma unroll
            for (int k = 0; k < HID; k++)
                acc += sAgg[nodeL][k] * sWl2[k * HID + j] + sH1[nodeL][k] * sWr2[k * HID + j];
            sH2[nodeL][j] = acc > 0.f ? acc : LEAKY * acc;
        }
    }
    __syncthreads();

    if (live) {
#pragma unroll
        for (int jj = 0; jj < 4; jj++) {
            int j = t * 4 + jj;
            float acc = 0.f;
#pragma unroll
            for (int k = 0; k < HID; k++) acc += sH2[nodeL][k] * sWse2[k * HID + j];
            sSkip[nodeL][j] = salpha * sH1[nodeL][j] + acc * SE3NORM;
        }
    }
    __syncthreads();

    float part = 0.f;
#pragma unroll
    for (int jj = 0; jj < 4; jj++) {
        int j = t * 4 + jj;
        float acc = sb3[j];
        if (live) {
#pragma unroll
            for (int k = 0; k < HID; k++) acc += sSkip[nodeL][k] * sW3[k * HID + j];
        }
        part += (acc > 0.f ? acc : 0.f) * sW4[j];
    }
    part += __shfl_xor(part, 1);
    part += __shfl_xor(part, 2);
    part += __shfl_xor(part, 4);
    if (live && t == 0) out[node] = part + sb4;
}

extern "C" void kernel_launch(void* const* d_in, const int* in_sizes, int n_in,
                              void* d_out, int out_size, void* d_ws, size_t ws_size,
                              hipStream_t stream) {
    const float* pos  = (const float*)d_in[0];
    const int*   ei   = (const int*)d_in[1];
    const float* Wl1  = (const float*)d_in[2];
    const float* bl1  = (const float*)d_in[3];
    const float* Wr1  = (const float*)d_in[4];
    const float* Wl2  = (const float*)d_in[5];
    const float* bl2  = (const float*)d_in[6];
    const float* Wr2  = (const float*)d_in[7];
    const float* Wse1 = (const float*)d_in[8];
    const float* Wse2 = (const float*)d_in[9];
    const float* W3   = (const float*)d_in[10];
    const float* b3   = (const float*)d_in[11];
    const float* W4   = (const float*)d_in[12];
    const float* b4   = (const float*)d_in[13];
    const float* alp  = (const float*)d_in[14];
    float* out = (float*)d_out;

    const int N = in_sizes[0] / 3;
    const int E = in_sizes[1] / 2;
    const int blk = 256;

    // ---- scheme NEW: two-level bucket sort, no global atomics ----
    const int B1 = (N + NBK - 1) / NBK;        // coarse buckets
    const int M2 = B1 * GA;                    // bh elements
    const int S2 = (M2 + SCAN_TILE - 1) / SCAN_TILE;   // scan tiles (must be <=256)
    // ws: bh[M2] bsum[256] bucketed[E] sorted_src[E] offsets[N+1] | h1[32N]
    {
        int* bh         = (int*)d_ws;
        int* bsum       = bh + M2;
        int* bucketed   = bsum + 256;
        int* sorted_src = bucketed + E;
        int* offsets    = sorted_src + E;
        uintptr_t hp = ((uintptr_t)(offsets + N + 1) + 15) & ~(uintptr_t)15;
        size_t need = (hp - (uintptr_t)d_ws) + (size_t)HID * N * sizeof(float);
        if (need <= ws_size && S2 <= 256) {
            float* h1 = (float*)hp;
            const int chunk = (E + GA - 1) / GA;
            const size_t ldsB = (size_t)B1 * sizeof(int);
            k_bhist<<<GA, 256, ldsB, stream>>>(ei, bh, E, B1, chunk);
            k_scan1<<<S2, 256, 0, stream>>>(bh, bsum, M2);
            k_scan2<<<1, 256, 0, stream>>>(bsum, S2);
            k_scan3<<<(M2 + blk - 1) / blk, blk, 0, stream>>>(bh, bsum, nullptr, M2, 0);
            k_bscatter<<<GA, 256, ldsB, stream>>>(ei, bh, bucketed, E, B1, chunk);
            k_bsort<<<B1, 256, 0, stream>>>(bh, bucketed, sorted_src, offsets, E, N, B1);
            k_node1<<<(N + blk - 1) / blk, blk, 0, stream>>>(offsets, sorted_src, pos,
                                                             Wl1, bl1, Wr1, Wse1, h1, N);
            k_node2out<<<(N + 31) / 32, 256, 0, stream>>>(offsets, sorted_src, h1,
                                                          Wl2, bl2, Wr2, Wse2,
                                                          W3, b3, W4, b4, alp, out, N);
            return;
        }
    }

    // ---- fallback: R4 global-atomic CSR build ----
    const int M = N + 1;
    const int B = (M + SCAN_TILE - 1) / SCAN_TILE;
    int* hist       = (int*)d_ws;
    int* offsets    = hist + M;
    int* bsum       = offsets + M;
    int* sorted_src = bsum + 256;
    int* aux        = sorted_src + E;
    uintptr_t hpA = ((uintptr_t)(aux + E) + 15) & ~(uintptr_t)15;
    uintptr_t hpB = ((uintptr_t)(aux + N) + 15) & ~(uintptr_t)15;
    size_t needA = (hpA - (uintptr_t)d_ws) + (size_t)HID * N * sizeof(float);
    const bool useRank = (needA <= ws_size);
    float* h1 = (float*)(useRank ? hpA : hpB);

    hipMemsetAsync(hist, 0, (size_t)M * sizeof(int), stream);
    const int egrid4 = (E / 4 + blk) / blk;
    if (useRank) {
        k_hist_rank<<<egrid4, blk, 0, stream>>>(ei, hist, aux, E);
    } else {
        k_hist<<<egrid4, blk, 0, stream>>>(ei, hist, E);
    }
    // scan hist -> offsets (separate arrays: copy path via in-place variant)
    // reuse in-place scan on hist, then offsets=hist pointer-swap
    k_scan1<<<B, 256, 0, stream>>>(hist, bsum, M);
    k_scan2<<<1, 256, 0, stream>>>(bsum, B);
    k_scan3<<<(M + blk - 1) / blk, blk, 0, stream>>>(hist, bsum, useRank ? nullptr : aux, M, N);
    int* offs = hist;   // scanned in place
    if (useRank) {
        k_scatter_rank<<<egrid4, blk, 0, stream>>>(ei, offs, aux, sorted_src, E);
    } else {
        k_scatter_atomic<<<egrid4, blk, 0, stream>>>(ei, aux, sorted_src, E);
    }
    k_node1<<<(N + blk - 1) / blk, blk, 0, stream>>>(offs, sorted_src, pos, Wl1, bl1, Wr1, Wse1, h1, N);
    k_node2out<<<(N + 31) / 32, 256, 0, stream>>>(offs, sorted_src, h1, Wl2, bl2, Wr2, Wse2,
                                                  W3, b3, W4, b4, alp, out, N);
}

// Round 6
// 288.825 us; speedup vs baseline: 6.4227x; 1.0071x over previous
//
#include <hip/hip_runtime.h>
#include <hip/hip_fp16.h>

#define HID 32
#define LEAKY 0.01f
#define SE3NORM 0.17677669529663687f   // 1/sqrt(32)
#define SCAN_TILE 1024                 // elements per scan block (256 thr x 4)
#define NBK 128                        // nodes per fine bucket
#define GA 256                         // pass-A blocks

// ======================= two-level bucket CSR build (no global atomics) =======================

// pass A1: per-block LDS histogram of coarse bucket (dst>>7); bh[b*GA + g] = count
__global__ void k_bhist(const int* __restrict__ ei, int* __restrict__ bh,
                        int E, int B1, int chunk) {
    extern __shared__ int lh[];                 // B1 ints
    int g = blockIdx.x;
    for (int i = threadIdx.x; i < B1; i += 256) lh[i] = 0;
    __syncthreads();
    int beg = g * chunk, end = min(E, beg + chunk);
    for (int e = beg + (int)threadIdx.x; e < end; e += 256)
        atomicAdd(&lh[ei[E + e] >> 7], 1);
    __syncthreads();
    for (int b = threadIdx.x; b < B1; b += 256) bh[b * GA + g] = lh[b];
}

// scan pass 1: per-tile exclusive scan IN PLACE + tile sums
__global__ void k_scan1(int* __restrict__ data, int* __restrict__ bsum, int M) {
    __shared__ int lds[256];
    int t = threadIdx.x;
    int base = blockIdx.x * SCAN_TILE + t * 4;
    int v0 = (base + 0 < M) ? data[base + 0] : 0;
    int v1 = (base + 1 < M) ? data[base + 1] : 0;
    int v2 = (base + 2 < M) ? data[base + 2] : 0;
    int v3 = (base + 3 < M) ? data[base + 3] : 0;
    int s = v0 + v1 + v2 + v3;
    lds[t] = s;
    __syncthreads();
    for (int off = 1; off < 256; off <<= 1) {
        int x = (t >= off) ? lds[t - off] : 0;
        __syncthreads();
        lds[t] += x;
        __syncthreads();
    }
    int ex = lds[t] - s;
    if (base + 0 < M) data[base + 0] = ex;
    if (base + 1 < M) data[base + 1] = ex + v0;
    if (base + 2 < M) data[base + 2] = ex + v0 + v1;
    if (base + 3 < M) data[base + 3] = ex + v0 + v1 + v2;
    if (t == 255) bsum[blockIdx.x] = lds[255];
}

// scan pass 2: exclusive scan of tile sums (single block, B<=256)
__global__ void k_scan2(int* __restrict__ bsum, int B) {
    __shared__ int lds[256];
    int t = threadIdx.x;
    int v = (t < B) ? bsum[t] : 0;
    lds[t] = v;
    __syncthreads();
    for (int off = 1; off < 256; off <<= 1) {
        int x = (t >= off) ? lds[t - off] : 0;
        __syncthreads();
        lds[t] += x;
        __syncthreads();
    }
    if (t < B) bsum[t] = lds[t] - v;
}

// scan pass 3: add tile prefix in place; optionally init cursor copy
__global__ void k_scan3(int* __restrict__ data, const int* __restrict__ bsum,
                        int* __restrict__ cursor, int M, int N) {
    int i = blockIdx.x * blockDim.x + threadIdx.x;
    if (i >= M) return;
    int off = data[i] + bsum[i / SCAN_TILE];
    data[i] = off;
    if (cursor && i < N) cursor[i] = off;
}

// pass A3: scatter edges into coarse buckets via LDS cursors; pack (localdst<<24)|src
__global__ void k_bscatter(const int* __restrict__ ei, const int* __restrict__ bh,
                           int* __restrict__ bucketed, int E, int B1, int chunk) {
    extern __shared__ int cur[];                // B1 ints
    int g = blockIdx.x;
    for (int b = threadIdx.x; b < B1; b += 256) cur[b] = bh[b * GA + g];
    __syncthreads();
    int beg = g * chunk, end = min(E, beg + chunk);
    for (int e = beg + (int)threadIdx.x; e < end; e += 256) {
        int d = ei[E + e];
        int s = ei[e];
        int b = d >> 7;
        int p = atomicAdd(&cur[b], 1);          // LDS atomic; slices disjoint per (b,g)
        bucketed[p] = s | ((d & (NBK - 1)) << 24);
    }
}

// pass B: per-bucket LDS counting sort -> sorted_src + offsets
__global__ void k_bsort(const int* __restrict__ bh, const int* __restrict__ bucketed,
                        int* __restrict__ sorted_src, int* __restrict__ offsets,
                        int E, int N, int B1) {
    __shared__ int hist[NBK], sc[NBK], base[NBK];
    int b = blockIdx.x;
    int t = threadIdx.x;
    int bs = bh[b * GA];
    int be = (b == B1 - 1) ? E : bh[(b + 1) * GA];
    if (t < NBK) hist[t] = 0;
    __syncthreads();
    for (int e = bs + t; e < be; e += 256)
        atomicAdd(&hist[bucketed[e] >> 24], 1);
    __syncthreads();
    int v = (t < NBK) ? hist[t] : 0;
    if (t < NBK) sc[t] = v;
    __syncthreads();
    for (int off = 1; off < NBK; off <<= 1) {
        int x = (t < NBK && t >= off) ? sc[t - off] : 0;
        __syncthreads();
        if (t < NBK) sc[t] += x;
        __syncthreads();
    }
    if (t < NBK) base[t] = sc[t] - v;           // exclusive
    __syncthreads();
    if (t < NBK) hist[t] = base[t];             // reuse hist as cursor
    __syncthreads();
    for (int e = bs + t; e < be; e += 256) {
        int pv = bucketed[e];
        int p = atomicAdd(&hist[pv >> 24], 1);
        sorted_src[bs + p] = pv & 0x00FFFFFF;
    }
    int node = b * NBK + t;
    if (t < NBK && node < N) offsets[node] = bs + base[t];
    if (b == B1 - 1 && t == 0) offsets[N] = E;
}

// ======================= fallback CSR build (global atomics, R4 path) =======================
__global__ void k_hist_rank(const int* __restrict__ ei, int* __restrict__ hist,
                            int* __restrict__ rank, int E) {
    int base = (blockIdx.x * blockDim.x + threadIdx.x) * 4;
#pragma unroll
    for (int u = 0; u < 4; u++) {
        int e = base + u;
        if (e < E) rank[e] = atomicAdd(&hist[ei[E + e]], 1);
    }
}
__global__ void k_hist(const int* __restrict__ ei, int* __restrict__ hist, int E) {
    int base = (blockIdx.x * blockDim.x + threadIdx.x) * 4;
#pragma unroll
    for (int u = 0; u < 4; u++) {
        int e = base + u;
        if (e < E) atomicAdd(&hist[ei[E + e]], 1);
    }
}
__global__ void k_scatter_rank(const int* __restrict__ ei, const int* __restrict__ offsets,
                               const int* __restrict__ rank, int* __restrict__ sorted_src, int E) {
    int base = (blockIdx.x * blockDim.x + threadIdx.x) * 4;
#pragma unroll
    for (int u = 0; u < 4; u++) {
        int e = base + u;
        if (e < E) sorted_src[offsets[ei[E + e]] + rank[e]] = ei[e];
    }
}
__global__ void k_scatter_atomic(const int* __restrict__ ei, int* __restrict__ cursor,
                                 int* __restrict__ sorted_src, int E) {
    int base = (blockIdx.x * blockDim.x + threadIdx.x) * 4;
#pragma unroll
    for (int u = 0; u < 4; u++) {
        int e = base + u;
        if (e < E) {
            int p = atomicAdd(&cursor[ei[E + e]], 1);
            sorted_src[p] = ei[e];
        }
    }
}

// ======================= node-level fused kernels =======================
// layer 1: agg1 segment sum + h1 = leaky(agg1@Wl1+bl1+x@Wr1)@Wse1*SE3NORM, stored fp16
__global__ void k_node1(const int* __restrict__ offsets, const int* __restrict__ sorted_src,
                        const float* __restrict__ pos,
                        const float* __restrict__ Wl1, const float* __restrict__ bl1,
                        const float* __restrict__ Wr1, const float* __restrict__ Wse1,
                        __half* __restrict__ h1out, int N) {
    __shared__ float sWl1[2 * HID], sWr1[2 * HID], sbl1[HID], sWse1[HID * HID];
    for (int i = threadIdx.x; i < 2 * HID; i += blockDim.x) { sWl1[i] = Wl1[i]; sWr1[i] = Wr1[i]; }
    for (int i = threadIdx.x; i < HID; i += blockDim.x) sbl1[i] = bl1[i];
    for (int i = threadIdx.x; i < HID * HID; i += blockDim.x) sWse1[i] = Wse1[i];
    __syncthreads();
    int i = blockIdx.x * blockDim.x + threadIdx.x;
    if (i >= N) return;
    int beg = offsets[i], end = offsets[i + 1];
    float a0 = 0.f, a1 = 0.f;
    int e = beg;
    for (; e + 4 <= end; e += 4) {
        int s0 = sorted_src[e], s1 = sorted_src[e + 1], s2 = sorted_src[e + 2], s3 = sorted_src[e + 3];
        a0 += pos[s0 * 3] + pos[s1 * 3] + pos[s2 * 3] + pos[s3 * 3];
        a1 += pos[s0 * 3 + 1] + pos[s1 * 3 + 1] + pos[s2 * 3 + 1] + pos[s3 * 3 + 1];
    }
    for (; e < end; e++) {
        int s = sorted_src[e];
        a0 += pos[s * 3];
        a1 += pos[s * 3 + 1];
    }
    float x0 = pos[3 * i], x1 = pos[3 * i + 1];
    float h[HID];
#pragma unroll
    for (int j = 0; j < HID; j++) {
        float v = a0 * sWl1[j] + a1 * sWl1[HID + j] + sbl1[j] + x0 * sWr1[j] + x1 * sWr1[HID + j];
        h[j] = v > 0.f ? v : LEAKY * v;
    }
    union Pack8 { __half h[8]; float4 v; };
#pragma unroll
    for (int c = 0; c < HID / 8; c++) {
        Pack8 p;
#pragma unroll
        for (int jj = 0; jj < 8; jj++) {
            int j = c * 8 + jj;
            float acc = 0.f;
#pragma unroll
            for (int k = 0; k < HID; k++) acc += h[k] * sWse1[k * HID + j];
            p.h[jj] = __float2half(acc * SE3NORM);
        }
        *(float4*)&h1out[(size_t)i * HID + c * 8] = p.v;
    }
}

// layer 2 + head: agg2 gather (fp16 h1, 8 thr/node) + conv2 + skip + MLP -> out
__global__ void k_node2out(const int* __restrict__ offsets, const int* __restrict__ sorted_src,
                           const __half* __restrict__ h1,
                           const float* __restrict__ Wl2, const float* __restrict__ bl2,
                           const float* __restrict__ Wr2, const float* __restrict__ Wse2,
                           const float* __restrict__ W3, const float* __restrict__ b3,
                           const float* __restrict__ W4, const float* __restrict__ b4,
                           const float* __restrict__ alpha_p,
                           float* __restrict__ out, int N) {
    __shared__ float sWl2[HID * HID], sWr2[HID * HID], sWse2[HID * HID], sW3[HID * HID];
    __shared__ float sbl2[HID], sb3[HID], sW4[HID];
    __shared__ float sb4, salpha;
    __shared__ float sA[32][HID + 1], sB[32][HID + 1];   // sA: agg2 -> h2 -> ; sB: h1 -> skip
    for (int i = threadIdx.x; i < HID * HID; i += blockDim.x) {
        sWl2[i] = Wl2[i]; sWr2[i] = Wr2[i]; sWse2[i] = Wse2[i]; sW3[i] = W3[i];
    }
    for (int i = threadIdx.x; i < HID; i += blockDim.x) { sbl2[i] = bl2[i]; sb3[i] = b3[i]; sW4[i] = W4[i]; }
    if (threadIdx.x == 0) { sb4 = b4[0]; salpha = alpha_p[0]; }
    __syncthreads();

    const int lt = threadIdx.x;
    const int nodeL = lt >> 3;       // 0..31
    const int t = lt & 7;            // feature chunk of 4
    const int node = blockIdx.x * 32 + nodeL;
    const bool live = node < N;

    float hvr[4];                    // own h1 fragment (registers)
    // phase 1: fp16 gather, 4-edge unrolled (8 B per lane per edge)
    if (live) {
        int beg = offsets[node], end = offsets[node + 1];
        float4 acc = make_float4(0.f, 0.f, 0.f, 0.f);
        int e = beg;
        for (; e + 4 <= end; e += 4) {
            int s0 = sorted_src[e], s1 = sorted_src[e + 1];
            int s2 = sorted_src[e + 2], s3 = sorted_src[e + 3];
            float2 r0 = *(const float2*)&h1[(size_t)s0 * HID + t * 4];
            float2 r1 = *(const float2*)&h1[(size_t)s1 * HID + t * 4];
            float2 r2 = *(const float2*)&h1[(size_t)s2 * HID + t * 4];
            float2 r3 = *(const float2*)&h1[(size_t)s3 * HID + t * 4];
            const float2* rs[4] = {&r0, &r1, &r2, &r3};
#pragma unroll
            for (int u = 0; u < 4; u++) {
                __half2 p01 = *(const __half2*)&rs[u]->x;
                __half2 p23 = *(const __half2*)&rs[u]->y;
                acc.x += __low2float(p01); acc.y += __high2float(p01);
                acc.z += __low2float(p23); acc.w += __high2float(p23);
            }
        }
        for (; e < end; e++) {
            int s = sorted_src[e];
            float2 r = *(const float2*)&h1[(size_t)s * HID + t * 4];
            __half2 p01 = *(const __half2*)&r.x;
            __half2 p23 = *(const __half2*)&r.y;
            acc.x += __low2float(p01); acc.y += __high2float(p01);
            acc.z += __low2float(p23); acc.w += __high2float(p23);
        }
        float2 ro = *(const float2*)&h1[(size_t)node * HID + t * 4];
        __half2 o01 = *(const __half2*)&ro.x;
        __half2 o23 = *(const __half2*)&ro.y;
        hvr[0] = __low2float(o01); hvr[1] = __high2float(o01);
        hvr[2] = __low2float(o23); hvr[3] = __high2float(o23);
        sA[nodeL][t * 4 + 0] = acc.x; sA[nodeL][t * 4 + 1] = acc.y;
        sA[nodeL][t * 4 + 2] = acc.z; sA[nodeL][t * 4 + 3] = acc.w;
        sB[nodeL][t * 4 + 0] = hvr[0]; sB[nodeL][t * 4 + 1] = hvr[1];
        sB[nodeL][t * 4 + 2] = hvr[2]; sB[nodeL][t * 4 + 3] = hvr[3];
    }
    __syncthreads();

    // phase 2: h2 = leaky(agg2@Wl2 + bl2 + h1@Wr2) -> registers
    float h2r[4];
    if (live) {
#pragma unroll
        for (int jj = 0; jj < 4; jj++) {
            int j = t * 4 + jj;
            float acc = sbl2[j];
#pragma unroll
            for (int k = 0; k < HID; k++)
                acc += sA[nodeL][k] * sWl2[k * HID + j] + sB[nodeL][k] * sWr2[k * HID + j];
            h2r[jj] = acc > 0.f ? acc : LEAKY * acc;
        }
    }
    __syncthreads();                 // all phase-2 reads done
    if (live) {
#pragma unroll
        for (int jj = 0; jj < 4; jj++) sA[nodeL][t * 4 + jj] = h2r[jj];
    }
    __syncthreads();                 // h2 visible in sA

    // phase 3: skip = alpha*h1(own regs) + (h2@Wse2)*SE3NORM -> sB (h1 no longer needed)
    if (live) {
#pragma unroll
        for (int jj = 0; jj < 4; jj++) {
            int j = t * 4 + jj;
            float acc = 0.f;
#pragma unroll
            for (int k = 0; k < HID; k++) acc += sA[nodeL][k] * sWse2[k * HID + j];
            sB[nodeL][j] = salpha * hvr[jj] + acc * SE3NORM;
        }
    }
    __syncthreads();                 // skip visible in sB

    // phase 4: pred = b4 + sum_j relu(skip@W3 + b3)_j * W4_j  (shfl-reduce 8 lanes)
    float part = 0.f;
#pragma unroll
    for (int jj = 0; jj < 4; jj++) {
        int j = t * 4 + jj;
        float acc = sb3[j];
        if (live) {
#pragma unroll
            for (int k = 0; k < HID; k++) acc += sB[nodeL][k] * sW3[k * HID + j];
        }
        part += (acc > 0.f ? acc : 0.f) * sW4[j];
    }
    part += __shfl_xor(part, 1);
    part += __shfl_xor(part, 2);
    part += __shfl_xor(part, 4);
    if (live && t == 0) out[node] = part + sb4;
}

extern "C" void kernel_launch(void* const* d_in, const int* in_sizes, int n_in,
                              void* d_out, int out_size, void* d_ws, size_t ws_size,
                              hipStream_t stream) {
    const float* pos  = (const float*)d_in[0];
    const int*   ei   = (const int*)d_in[1];
    const float* Wl1  = (const float*)d_in[2];
    const float* bl1  = (const float*)d_in[3];
    const float* Wr1  = (const float*)d_in[4];
    const float* Wl2  = (const float*)d_in[5];
    const float* bl2  = (const float*)d_in[6];
    const float* Wr2  = (const float*)d_in[7];
    const float* Wse1 = (const float*)d_in[8];
    const float* Wse2 = (const float*)d_in[9];
    const float* W3   = (const float*)d_in[10];
    const float* b3   = (const float*)d_in[11];
    const float* W4   = (const float*)d_in[12];
    const float* b4   = (const float*)d_in[13];
    const float* alp  = (const float*)d_in[14];
    float* out = (float*)d_out;

    const int N = in_sizes[0] / 3;
    const int E = in_sizes[1] / 2;
    const int blk = 256;
    const size_t h1bytes = (size_t)N * HID * sizeof(__half);

    // ---- scheme NEW: two-level bucket sort, no global atomics ----
    const int B1 = (N + NBK - 1) / NBK;
    const int M2 = B1 * GA;
    const int S2 = (M2 + SCAN_TILE - 1) / SCAN_TILE;
    {
        int* bh         = (int*)d_ws;
        int* bsum       = bh + M2;
        int* bucketed   = bsum + 256;
        int* sorted_src = bucketed + E;
        int* offsets    = sorted_src + E;
        uintptr_t hp = ((uintptr_t)(offsets + N + 1) + 15) & ~(uintptr_t)15;
        size_t need = (hp - (uintptr_t)d_ws) + h1bytes;
        if (need <= ws_size && S2 <= 256) {
            __half* h1 = (__half*)hp;
            const int chunk = (E + GA - 1) / GA;
            const size_t ldsB = (size_t)B1 * sizeof(int);
            k_bhist<<<GA, 256, ldsB, stream>>>(ei, bh, E, B1, chunk);
            k_scan1<<<S2, 256, 0, stream>>>(bh, bsum, M2);
            k_scan2<<<1, 256, 0, stream>>>(bsum, S2);
            k_scan3<<<(M2 + blk - 1) / blk, blk, 0, stream>>>(bh, bsum, nullptr, M2, 0);
            k_bscatter<<<GA, 256, ldsB, stream>>>(ei, bh, bucketed, E, B1, chunk);
            k_bsort<<<B1, 256, 0, stream>>>(bh, bucketed, sorted_src, offsets, E, N, B1);
            k_node1<<<(N + blk - 1) / blk, blk, 0, stream>>>(offsets, sorted_src, pos,
                                                             Wl1, bl1, Wr1, Wse1, h1, N);
            k_node2out<<<(N + 31) / 32, 256, 0, stream>>>(offsets, sorted_src, h1,
                                                          Wl2, bl2, Wr2, Wse2,
                                                          W3, b3, W4, b4, alp, out, N);
            return;
        }
    }

    // ---- fallback: R4 global-atomic CSR build ----
    const int M = N + 1;
    const int B = (M + SCAN_TILE - 1) / SCAN_TILE;
    int* hist       = (int*)d_ws;
    int* offsets    = hist + M;   // unused (in-place scan) but keeps layout roomy
    int* bsum       = offsets + M;
    int* sorted_src = bsum + 256;
    int* aux        = sorted_src + E;
    uintptr_t hpA = ((uintptr_t)(aux + E) + 15) & ~(uintptr_t)15;
    uintptr_t hpB = ((uintptr_t)(aux + N) + 15) & ~(uintptr_t)15;
    size_t needA = (hpA - (uintptr_t)d_ws) + h1bytes;
    const bool useRank = (needA <= ws_size);
    __half* h1 = (__half*)(useRank ? hpA : hpB);

    hipMemsetAsync(hist, 0, (size_t)M * sizeof(int), stream);
    const int egrid4 = (E / 4 + blk) / blk;
    if (useRank) {
        k_hist_rank<<<egrid4, blk, 0, stream>>>(ei, hist, aux, E);
    } else {
        k_hist<<<egrid4, blk, 0, stream>>>(ei, hist, E);
    }
    k_scan1<<<B, 256, 0, stream>>>(hist, bsum, M);
    k_scan2<<<1, 256, 0, stream>>>(bsum, B);
    k_scan3<<<(M + blk - 1) / blk, blk, 0, stream>>>(hist, bsum, useRank ? nullptr : aux, M, N);
    int* offs = hist;
    if (useRank) {
        k_scatter_rank<<<egrid4, blk, 0, stream>>>(ei, offs, aux, sorted_src, E);
    } else {
        k_scatter_atomic<<<egrid4, blk, 0, stream>>>(ei, aux, sorted_src, E);
    }
    k_node1<<<(N + blk - 1) / blk, blk, 0, stream>>>(offs, sorted_src, pos, Wl1, bl1, Wr1, Wse1, h1, N);
    k_node2out<<<(N + 31) / 32, 256, 0, stream>>>(offs, sorted_src, h1, Wl2, bl2, Wr2, Wse2,
                                                  W3, b3, W4, b4, alp, out, N);
}